// Round 6
// baseline (1834.489 us; speedup 1.0000x reference)
//
#include <hip/hip_runtime.h>

#define BSZ  5
#define PROJ 1000
#define DET  513
#define IMG  362
#define NPIX (IMG * IMG)          // 131044
#define SINO (PROJ * DET)         // 513000
#define NNZ  20000000

#define NSHARD     2
#define SHARD_COLS 256500            // SINO/2
#define NRG        2048              // row groups of 64 px (row>>6)
#define NBIN       (NRG * NSHARD)    // 4096; bin = ((row>>6)<<1) | (col>=SHARD_COLS)

#define SBLK       256               // count/scatter blocks
#define CHUNK      78128             // per-block record chunk (mult of 4; 255*CHUNK+77360 = NNZ)
#define CS_THREADS 1024

#define RS_THREADS 512
#define STAGE_CAP  4096              // staged records per chunk (32 KB LDS)

typedef int      i32x4 __attribute__((ext_vector_type(4)));
typedef float    f32x4 __attribute__((ext_vector_type(4)));
typedef unsigned u32x4 __attribute__((ext_vector_type(4)));

// ---------------- fast path ----------------

// sino -> bf16 packed table: [col] = {b0|b1<<16, b2|b3<<16, b4, 0} (16 B, line-aligned)
__global__ void k_sino_bf16(const float* __restrict__ sino, u32x4* __restrict__ sino_b) {
    const int c = blockIdx.x * blockDim.x + threadIdx.x;
    if (c < SINO) {
        unsigned b[5];
#pragma unroll
        for (int k = 0; k < 5; ++k) {
            const unsigned u = __float_as_uint(sino[(size_t)k * SINO + c]);
            b[k] = (u + 0x7FFFu + ((u >> 16) & 1u)) >> 16;   // RNE to bf16
        }
        u32x4 o;
        o.x = b[0] | (b[1] << 16);
        o.y = b[2] | (b[3] << 16);
        o.z = b[4];
        o.w = 0u;
        sino_b[c] = o;
    }
}

__device__ __forceinline__ int bin_of(int row, int col) {
    return ((row >> 6) << 1) | (col >= SHARD_COLS ? 1 : 0);
}

// count + per-block exclusive scan -> loc[blk][bin]
__global__ __launch_bounds__(CS_THREADS) void k_count(
        const int* __restrict__ rows, const int* __restrict__ cols,
        unsigned* __restrict__ loc) {
    __shared__ unsigned c[NBIN];          // 16 KB
    __shared__ unsigned aux[CS_THREADS];  // 4 KB
    const int t = threadIdx.x;
    for (int j = t; j < NBIN; j += CS_THREADS) c[j] = 0u;
    __syncthreads();
    const int lo = blockIdx.x * CHUNK;
    const int hi = (lo + CHUNK < NNZ) ? lo + CHUNK : NNZ;
    for (int i4 = lo / 4 + t; i4 * 4 < hi; i4 += CS_THREADS) {
        const i32x4 r = __builtin_nontemporal_load(((const i32x4*)rows) + i4);
        const i32x4 q = __builtin_nontemporal_load(((const i32x4*)cols) + i4);
        atomicAdd(&c[bin_of(r.x, q.x)], 1u);
        atomicAdd(&c[bin_of(r.y, q.y)], 1u);
        atomicAdd(&c[bin_of(r.z, q.z)], 1u);
        atomicAdd(&c[bin_of(r.w, q.w)], 1u);
    }
    __syncthreads();
    // exclusive scan of the 4096 counters, 4 per thread
    const unsigned v0 = c[t * 4 + 0], v1 = c[t * 4 + 1], v2 = c[t * 4 + 2], v3 = c[t * 4 + 3];
    const unsigned s = v0 + v1 + v2 + v3;
    aux[t] = s;
    __syncthreads();
    for (int off = 1; off < CS_THREADS; off <<= 1) {
        const unsigned x = (t >= off) ? aux[t - off] : 0u;
        __syncthreads();
        aux[t] += x;
        __syncthreads();
    }
    unsigned run = aux[t] - s;
    unsigned* dst = loc + (size_t)blockIdx.x * NBIN + t * 4;
    dst[0] = run; run += v0;
    dst[1] = run; run += v1;
    dst[2] = run; run += v2;
    dst[3] = run;
}

// scatter into block-major bin-sorted order: dest = blk*CHUNK + loc[blk][bin] + claim
__global__ __launch_bounds__(CS_THREADS) void k_scatter(
        const float* __restrict__ vals, const int* __restrict__ rows,
        const int* __restrict__ cols, const unsigned* __restrict__ loc,
        unsigned long long* __restrict__ rec) {
    __shared__ unsigned cur[NBIN];   // 16 KB: cursor starts at loc, atomicAdd claims
    const int t = threadIdx.x;
    for (int j = t; j < NBIN; j += CS_THREADS)
        cur[j] = loc[(size_t)blockIdx.x * NBIN + j];
    __syncthreads();
    const int lo = blockIdx.x * CHUNK;
    const int hi = (lo + CHUNK < NNZ) ? lo + CHUNK : NNZ;
    unsigned long long* base = rec + lo;
    for (int i4 = lo / 4 + t; i4 * 4 < hi; i4 += CS_THREADS) {
        const i32x4 r = __builtin_nontemporal_load(((const i32x4*)rows) + i4);
        const i32x4 q = __builtin_nontemporal_load(((const i32x4*)cols) + i4);
        const f32x4 v = __builtin_nontemporal_load(((const f32x4*)vals) + i4);
#define EMIT(RR, QQ, VV) do {                                                     \
        const int bn = bin_of(RR, QQ);                                            \
        const unsigned slot = atomicAdd(&cur[bn], 1u);                            \
        const unsigned long long rv =                                             \
            ((unsigned long long)((unsigned)(((RR) & 63) << 19) | (unsigned)(QQ)) << 32) \
            | (unsigned long long)__float_as_uint(VV);                            \
        __builtin_nontemporal_store(rv, base + slot);                             \
    } while (0)
        EMIT(r.x, q.x, v.x);
        EMIT(r.y, q.y, v.y);
        EMIT(r.z, q.z, v.z);
        EMIT(r.w, q.w, v.w);
#undef EMIT
    }
}

// atomic-free accumulation: block = bin (64 px), lane owns 1 px, register accumulate
__global__ __launch_bounds__(RS_THREADS) void k_rscan(
        const unsigned long long* __restrict__ rec,
        const unsigned* __restrict__ loc,
        const u32x4* __restrict__ sino_b,
        float* __restrict__ acc) {
    __shared__ unsigned fstart[SBLK];
    __shared__ unsigned fdst[SBLK + 1];
    __shared__ unsigned long long srec[STAGE_CAP];   // 32 KB (reused as merge buffer)
    const int t = threadIdx.x;
    const int bin = blockIdx.x;
    if (t < SBLK) {
        const unsigned l0 = loc[(size_t)t * NBIN + bin];
        unsigned l1;
        if (bin == NBIN - 1) {
            const int cs = (t * CHUNK + CHUNK < NNZ) ? CHUNK : NNZ - t * CHUNK;
            l1 = (unsigned)cs;
        } else {
            l1 = loc[(size_t)t * NBIN + bin + 1];
        }
        fstart[t] = (unsigned)(t * CHUNK) + l0;
        if (t == 0) fdst[0] = 0u;
        fdst[t + 1] = l1 - l0;
    }
    __syncthreads();
    // scan fragment sizes -> fdst (prefix), 8 rounds over 256 entries
    for (int off = 1; off < SBLK; off <<= 1) {
        unsigned x = 0u;
        if (t < SBLK && t >= off) x = fdst[t + 1 - off];
        __syncthreads();
        if (t < SBLK) fdst[t + 1] += x;
        __syncthreads();
    }
    const unsigned T = fdst[SBLK];
    const int lane = t & 63;
    const int w = t >> 6;
    float a0 = 0.f, a1 = 0.f, a2 = 0.f, a3 = 0.f, a4 = 0.f, a5 = 0.f;

    for (unsigned cb = 0; cb < T; cb += STAGE_CAP) {
        const int n = (int)((T - cb < STAGE_CAP) ? (T - cb) : (unsigned)STAGE_CAP);
        // stage records: logical index -> fragment via fixed-depth binary search
        for (int j = t; j < n; j += RS_THREADS) {
            const unsigned jj = cb + (unsigned)j;
            int f = 0;
#pragma unroll
            for (int sft = 128; sft; sft >>= 1) {
                const int nf = f + sft;
                if (fdst[nf] <= jj) f = nf;
            }
            srec[j] = __builtin_nontemporal_load(rec + fstart[f] + (jj - fdst[f]));
        }
        __syncthreads();
        // broadcast-scan: wave w scans its slice, lane l accumulates pixel l
        const int sl = (n + 7) >> 3;
        const int mylo = w * sl;
        const int myhi = (mylo + sl < n) ? (mylo + sl) : n;
        for (int i = mylo; i < myhi; ++i) {
            const unsigned long long u = srec[i];        // LDS broadcast (uniform addr)
            const unsigned pk = (unsigned)(u >> 32);
            const float v = __uint_as_float((unsigned)(u & 0xFFFFFFFFull));
            const int col = (int)(pk & 0x7FFFFu);
            const int lr  = (int)(pk >> 19);
            const u32x4 sv = sino_b[col];                // uniform 16B load, L2-resident shard
            const float m = (lr == lane) ? v : 0.f;
            a0 += m * __uint_as_float(sv.x << 16);
            a1 += m * __uint_as_float(sv.x & 0xFFFF0000u);
            a2 += m * __uint_as_float(sv.y << 16);
            a3 += m * __uint_as_float(sv.y & 0xFFFF0000u);
            a4 += m * __uint_as_float(sv.z << 16);
            a5 += m;
        }
        __syncthreads();
    }
    // merge 8 wave-partials (disjoint LDS writes, then tree sum) -> acc[bin][64][6]
    float* part = (float*)srec;
    float* pw = part + (size_t)(w * 64 + lane) * 6;
    pw[0] = a0; pw[1] = a1; pw[2] = a2; pw[3] = a3; pw[4] = a4; pw[5] = a5;
    __syncthreads();
    if (t < 384) {
        const int px = t / 6, s6 = t - px * 6;
        float g = 0.f;
#pragma unroll
        for (int ww = 0; ww < 8; ++ww) g += part[(size_t)(ww * 64 + px) * 6 + s6];
        acc[(size_t)bin * 384 + t] = g;
    }
}

// sum 2 shards, divide, write [BSZ][NPIX]
__global__ void k_final(const float* __restrict__ acc, float* __restrict__ out) {
    const int p = blockIdx.x * blockDim.x + threadIdx.x;
    if (p < NPIX) {
        const int rg = p >> 6, l = p & 63;
        const float* A = acc + (size_t)(rg << 1) * 384 + l * 6;
        const float* B = A + 384;
        const float inv = 1.f / (A[5] + B[5]);
        out[0 * (size_t)NPIX + p] = (A[0] + B[0]) * inv;
        out[1 * (size_t)NPIX + p] = (A[1] + B[1]) * inv;
        out[2 * (size_t)NPIX + p] = (A[2] + B[2]) * inv;
        out[3 * (size_t)NPIX + p] = (A[3] + B[3]) * inv;
        out[4 * (size_t)NPIX + p] = (A[4] + B[4]) * inv;
    }
}

// ---------------- fallback (tiny workspace) ----------------

__global__ void bp_scatter_fb_kernel(const float* __restrict__ sino,
                                     const float* __restrict__ vals,
                                     const int*   __restrict__ rows,
                                     const int*   __restrict__ cols,
                                     float* __restrict__ acc) {
    const long long stride = (long long)gridDim.x * blockDim.x;
    for (long long i = (long long)blockIdx.x * blockDim.x + threadIdx.x;
         i < NNZ; i += stride) {
        const float v = vals[i];
        const int   r = rows[i];
        const int   c = cols[i];
        atomicAdd(acc + (size_t)BSZ * NPIX + r, v);
#pragma unroll
        for (int b = 0; b < BSZ; ++b)
            atomicAdd(acc + (size_t)b * NPIX + r, v * sino[(size_t)b * SINO + c]);
    }
}

__global__ void bp_divide_fb_kernel(const float* __restrict__ acc,
                                    float* __restrict__ out) {
    const int i = blockIdx.x * blockDim.x + threadIdx.x;
    if (i < BSZ * NPIX) {
        const int p = i % NPIX;
        out[i] = acc[i] / acc[(size_t)BSZ * NPIX + p];
    }
}

// ---------------- launch ----------------

extern "C" void kernel_launch(void* const* d_in, const int* in_sizes, int n_in,
                              void* d_out, int out_size, void* d_ws, size_t ws_size,
                              hipStream_t stream) {
    const float* sino = (const float*)d_in[0];
    const float* vals = (const float*)d_in[1];
    const int*   rows = (const int*)d_in[2];
    const int*   cols = (const int*)d_in[3];
    float* out = (float*)d_out;

    // workspace (bytes):
    //   rec    : NNZ * 8            = 160,000,000
    //   sino_b : SINO * 16          =   8,208,000
    //   acc    : NBIN * 384 * 4     =   6,291,456
    //   loc    : SBLK * NBIN * 4    =   4,194,304
    //   total                       = 178,693,760  (< round-5's proven 181.8 MB)
    const size_t rec_b    = (size_t)NNZ * 8;
    const size_t sino_b_b = (size_t)SINO * 16;
    const size_t acc_b    = (size_t)NBIN * 384 * 4;
    const size_t loc_b    = (size_t)SBLK * NBIN * 4;
    const size_t need = rec_b + sino_b_b + acc_b + loc_b;

    if (ws_size >= need) {
        char* w = (char*)d_ws;
        unsigned long long* rec = (unsigned long long*)w;   w += rec_b;
        u32x4*    sinob = (u32x4*)w;                        w += sino_b_b;
        float*    acc   = (float*)w;                        w += acc_b;
        unsigned* loc   = (unsigned*)w;

        k_sino_bf16<<<(SINO + 255) / 256, 256, 0, stream>>>(sino, sinob);
        k_count<<<SBLK, CS_THREADS, 0, stream>>>(rows, cols, loc);
        k_scatter<<<SBLK, CS_THREADS, 0, stream>>>(vals, rows, cols, loc, rec);
        k_rscan<<<NBIN, RS_THREADS, 0, stream>>>(rec, loc, sinob, acc);
        k_final<<<(NPIX + 255) / 256, 256, 0, stream>>>(acc, out);
    } else {
        float* acc = (float*)d_ws;
        (void)hipMemsetAsync(acc, 0, (size_t)(BSZ + 1) * NPIX * sizeof(float), stream);
        bp_scatter_fb_kernel<<<2048, 256, 0, stream>>>(sino, vals, rows, cols, acc);
        bp_divide_fb_kernel<<<(BSZ * NPIX + 255) / 256, 256, 0, stream>>>(acc, out);
    }
}

// Round 7
// 378.210 us; speedup vs baseline: 4.8505x; 4.8505x over previous
//
#include <hip/hip_runtime.h>

#define BSZ  5
#define PROJ 1000
#define DET  513
#define IMG  362
#define NPIX (IMG * IMG)          // 131044
#define SINO (PROJ * DET)         // 513000
#define NNZ  20000000

#define NSHARD     4
#define SHARD_COLS (SINO / NSHARD)   // 128250
#define RB_SHIFT   10
#define RB_PX      1024
#define NRBIN      128               // ceil(NPIX/1024)
#define NBIN       (NRBIN * NSHARD)  // 512, bin = (row>>10)*4 + col/SHARD_COLS

#define SCAT_BLOCKS  256
#define SCAT_THREADS 1024
#define CHUNK        78128           // ceil(NNZ/256) rounded to mult of 16

#define ACC_THREADS  512

// fixed-point accumulation constants
#define FXSCALE 262144.0f            // 2^18
#define FXINV   (1.0f / 262144.0f)
#define FXBIAS  4194304              // 2^22: keeps packed low halves positive

typedef int      i32x4 __attribute__((ext_vector_type(4)));
typedef float    f32x4 __attribute__((ext_vector_type(4)));
typedef float    f32x2 __attribute__((ext_vector_type(2)));
typedef unsigned u32x4 __attribute__((ext_vector_type(4)));

// ---- no-return LDS atomics (fire-and-forget; avoid rtn/waitcnt serialization)
// gfx9+: low 32 bits of a generic LDS pointer == LDS byte offset (4GB-aligned aperture)
__device__ __forceinline__ unsigned lds_off(const void* p) {
    return (unsigned)(size_t)p;
}
__device__ __forceinline__ void ds_add_u32_nr(unsigned off, unsigned v) {
    asm volatile("ds_add_u32 %0, %1" :: "v"(off), "v"(v) : "memory");
}
__device__ __forceinline__ void ds_add_u64_nr(unsigned off, unsigned long long v) {
    asm volatile("ds_add_u64 %0, %1" :: "v"(off), "v"(v) : "memory");
}

// ---------------- fast path kernels ----------------

// sino -> bf16 packed table: [col] = u32x4 {b0|b1<<16, b2|b3<<16, b4, 0}
__global__ void k_sino_bf16(const float* __restrict__ sino, u32x4* __restrict__ sino_b) {
    const int c = blockIdx.x * blockDim.x + threadIdx.x;
    if (c < SINO) {
        unsigned b[5];
#pragma unroll
        for (int k = 0; k < 5; ++k) {
            const unsigned u = __float_as_uint(sino[(size_t)k * SINO + c]);
            b[k] = (u + 0x7FFFu + ((u >> 16) & 1u)) >> 16;   // RNE to bf16
        }
        u32x4 o;
        o.x = b[0] | (b[1] << 16);
        o.y = b[2] | (b[3] << 16);
        o.z = b[4];
        o.w = 0u;
        sino_b[c] = o;
    }
}

__device__ __forceinline__ int bin_of(int row, int col) {
    return ((row >> RB_SHIFT) << 2) | (col / SHARD_COLS);
}

// pass A: per-(block,bin) exact counts (no global atomics)
__global__ __launch_bounds__(SCAT_THREADS) void k_count(
        const int* __restrict__ rows, const int* __restrict__ cols,
        unsigned* __restrict__ cnt) {
    __shared__ unsigned c[NBIN];
    const int t = threadIdx.x;
    for (int j = t; j < NBIN; j += SCAT_THREADS) c[j] = 0u;
    __syncthreads();
    const int lo = blockIdx.x * CHUNK;
    const int hi = (lo + CHUNK < NNZ) ? lo + CHUNK : NNZ;
    for (int i4 = lo / 4 + t; i4 * 4 < hi; i4 += SCAT_THREADS) {
        const i32x4 r = __builtin_nontemporal_load(((const i32x4*)rows) + i4);
        const i32x4 q = __builtin_nontemporal_load(((const i32x4*)cols) + i4);
        ds_add_u32_nr(lds_off(&c[bin_of(r.x, q.x)]), 1u);
        ds_add_u32_nr(lds_off(&c[bin_of(r.y, q.y)]), 1u);
        ds_add_u32_nr(lds_off(&c[bin_of(r.z, q.z)]), 1u);
        ds_add_u32_nr(lds_off(&c[bin_of(r.w, q.w)]), 1u);
    }
    __syncthreads();
    for (int j = t; j < NBIN; j += SCAT_THREADS)
        cnt[(size_t)blockIdx.x * NBIN + j] = c[j];
}

// per-bin totals: block b reduces cnt[*][b]
__global__ void k_tot(const unsigned* __restrict__ cnt, unsigned* __restrict__ tot) {
    __shared__ unsigned s[SCAT_BLOCKS];
    const int b = blockIdx.x, t = threadIdx.x;
    s[t] = cnt[(size_t)t * NBIN + b];
    __syncthreads();
    for (int o = SCAT_BLOCKS / 2; o > 0; o >>= 1) {
        if (t < o) s[t] += s[t + o];
        __syncthreads();
    }
    if (t == 0) tot[b] = s[0];
}

// exclusive scan of tot -> binoff (one block of NBIN threads)
__global__ void k_scan(const unsigned* __restrict__ tot, unsigned* __restrict__ binoff) {
    __shared__ unsigned s[NBIN];
    const int t = threadIdx.x;
    const unsigned my = tot[t];
    s[t] = my;
    __syncthreads();
    for (int o = 1; o < NBIN; o <<= 1) {
        const unsigned v = (t >= o) ? s[t - o] : 0u;
        __syncthreads();
        s[t] += v;
        __syncthreads();
    }
    binoff[t] = s[t] - my;
    if (t == NBIN - 1) binoff[NBIN] = (unsigned)NNZ;
}

// per-(block,bin) start positions: block b scans cnt[blk][b] over blk
__global__ void k_base(const unsigned* __restrict__ cnt,
                       const unsigned* __restrict__ binoff,
                       unsigned* __restrict__ base) {
    __shared__ unsigned s[SCAT_BLOCKS];
    const int b = blockIdx.x, t = threadIdx.x;
    const unsigned my = cnt[(size_t)t * NBIN + b];
    s[t] = my;
    __syncthreads();
    for (int o = 1; o < SCAT_BLOCKS; o <<= 1) {
        const unsigned v = (t >= o) ? s[t - o] : 0u;
        __syncthreads();
        s[t] += v;
        __syncthreads();
    }
    base[(size_t)t * NBIN + b] = binoff[b] + s[t] - my;
}

// pass B: scatter records {val, lr<<19|col} into bin-contiguous order
__global__ __launch_bounds__(SCAT_THREADS) void k_scatter(
        const float* __restrict__ vals, const int* __restrict__ rows,
        const int* __restrict__ cols, const unsigned* __restrict__ base,
        f32x2* __restrict__ rec) {
    __shared__ unsigned bs[NBIN];
    __shared__ unsigned c2[NBIN];
    const int t = threadIdx.x;
    for (int j = t; j < NBIN; j += SCAT_THREADS) {
        bs[j] = base[(size_t)blockIdx.x * NBIN + j];
        c2[j] = 0u;
    }
    __syncthreads();
    const int lo = blockIdx.x * CHUNK;
    const int hi = (lo + CHUNK < NNZ) ? lo + CHUNK : NNZ;
    for (int i4 = lo / 4 + t; i4 * 4 < hi; i4 += SCAT_THREADS) {
        const i32x4 r = __builtin_nontemporal_load(((const i32x4*)rows) + i4);
        const i32x4 q = __builtin_nontemporal_load(((const i32x4*)cols) + i4);
        const f32x4 v = __builtin_nontemporal_load(((const f32x4*)vals) + i4);
#define EMIT(RR, QQ, VV) do {                                            \
        const int bin = bin_of(RR, QQ);                                  \
        const unsigned slot = atomicAdd(&c2[bin], 1u);                   \
        const unsigned packed = ((unsigned)((RR) & (RB_PX - 1)) << 19) | (unsigned)(QQ); \
        f32x2 rc; rc.x = (VV); rc.y = __uint_as_float(packed);           \
        rec[bs[bin] + slot] = rc;                                        \
    } while (0)
        EMIT(r.x, q.x, v.x);
        EMIT(r.y, q.y, v.y);
        EMIT(r.z, q.z, v.z);
        EMIT(r.w, q.w, v.w);
#undef EMIT
    }
}

// accumulate one bin in LDS with fixed-point packed u64 no-rtn atomics.
// per pixel: 5 u64 slots (40 B): [0]=(s1:s0+bias) [1]=(s3:s2+bias) [2]=(s5:s4+bias) [3].lo=n
__global__ __launch_bounds__(ACC_THREADS) void k_accum(
        const f32x2* __restrict__ rec, const u32x4* __restrict__ sino_b,
        const unsigned* __restrict__ binoff, float* __restrict__ acc) {
    __shared__ unsigned long long l8[RB_PX * 5];   // 40 KB
    const int t = threadIdx.x;
    for (int j = t; j < RB_PX * 5; j += ACC_THREADS) l8[j] = 0ull;
    __syncthreads();
    const int bin = blockIdx.x;
    const unsigned lo = binoff[bin], hi = binoff[bin + 1];
    for (unsigned i = lo + t; i < hi; i += ACC_THREADS) {
        const f32x2 rc = __builtin_nontemporal_load(rec + i);
        const unsigned u = __float_as_uint(rc.y);
        const int col = (int)(u & 0x7FFFFu);
        const int lr  = (int)(u >> 19);
        const u32x4 sv = sino_b[col];
        const float v = rc.x;
        const int q0 = __float2int_rn(v * __uint_as_float(sv.x << 16)         * FXSCALE);
        const int q1 = __float2int_rn(v * __uint_as_float(sv.x & 0xFFFF0000u) * FXSCALE);
        const int q2 = __float2int_rn(v * __uint_as_float(sv.y << 16)         * FXSCALE);
        const int q3 = __float2int_rn(v * __uint_as_float(sv.y & 0xFFFF0000u) * FXSCALE);
        const int q4 = __float2int_rn(v * __uint_as_float(sv.z << 16)         * FXSCALE);
        const int q5 = __float2int_rn(v * FXSCALE);
        const unsigned base = lds_off(&l8[(unsigned)lr * 5u]);
        ds_add_u64_nr(base,
            ((unsigned long long)(unsigned)q1 << 32) | (unsigned)(q0 + FXBIAS));
        ds_add_u64_nr(base + 8,
            ((unsigned long long)(unsigned)q3 << 32) | (unsigned)(q2 + FXBIAS));
        ds_add_u64_nr(base + 16,
            ((unsigned long long)(unsigned)q5 << 32) | (unsigned)(q4 + FXBIAS));
        ds_add_u32_nr(base + 24, 1u);
    }
    __syncthreads();
    // decode fixed-point -> float, store acc[bin][px][6]
    float* dst = acc + (size_t)bin * (RB_PX * 6);
    for (int px = t; px < RB_PX; px += ACC_THREADS) {
        const unsigned long long a0 = l8[px * 5 + 0];
        const unsigned long long a1 = l8[px * 5 + 1];
        const unsigned long long a2 = l8[px * 5 + 2];
        const unsigned n = (unsigned)(l8[px * 5 + 3] & 0xFFFFFFFFull);
        const long long nb = (long long)n * FXBIAS;
        float* d = dst + px * 6;
        d[0] = (float)((long long)(unsigned)(a0 & 0xFFFFFFFFull) - nb) * FXINV;
        d[1] = (float)((int)(a0 >> 32)) * FXINV;
        d[2] = (float)((long long)(unsigned)(a1 & 0xFFFFFFFFull) - nb) * FXINV;
        d[3] = (float)((int)(a1 >> 32)) * FXINV;
        d[4] = (float)((long long)(unsigned)(a2 & 0xFFFFFFFFull) - nb) * FXINV;
        d[5] = (float)((int)(a2 >> 32)) * FXINV;
    }
}

// sum 4 shards per pixel, divide, write [BSZ][NPIX]
__global__ void k_reduce(const float* __restrict__ acc, float* __restrict__ out) {
    const int p = blockIdx.x * blockDim.x + threadIdx.x;
    if (p < NPIX) {
        const int rbin = p >> RB_SHIFT, lr = p & (RB_PX - 1);
        float n0 = 0.f, n1 = 0.f, n2 = 0.f, n3 = 0.f, n4 = 0.f, den = 0.f;
#pragma unroll
        for (int s = 0; s < NSHARD; ++s) {
            const float* b = acc + ((size_t)(rbin * NSHARD + s) * RB_PX + lr) * 6;
            n0 += b[0]; n1 += b[1]; n2 += b[2];
            n3 += b[3]; n4 += b[4]; den += b[5];
        }
        const float inv = 1.f / den;
        out[0 * (size_t)NPIX + p] = n0 * inv;
        out[1 * (size_t)NPIX + p] = n1 * inv;
        out[2 * (size_t)NPIX + p] = n2 * inv;
        out[3 * (size_t)NPIX + p] = n3 * inv;
        out[4 * (size_t)NPIX + p] = n4 * inv;
    }
}

// ---------------- fallback kernels (small workspace) ----------------

__global__ void bp_scatter_fb_kernel(const float* __restrict__ sino,
                                     const float* __restrict__ vals,
                                     const int*   __restrict__ rows,
                                     const int*   __restrict__ cols,
                                     float* __restrict__ acc) {
    const long long stride = (long long)gridDim.x * blockDim.x;
    for (long long i = (long long)blockIdx.x * blockDim.x + threadIdx.x;
         i < NNZ; i += stride) {
        const float v = vals[i];
        const int   r = rows[i];
        const int   c = cols[i];
        atomicAdd(acc + (size_t)BSZ * NPIX + r, v);
#pragma unroll
        for (int b = 0; b < BSZ; ++b)
            atomicAdd(acc + (size_t)b * NPIX + r, v * sino[(size_t)b * SINO + c]);
    }
}

__global__ void bp_divide_fb_kernel(const float* __restrict__ acc,
                                    float* __restrict__ out) {
    const int i = blockIdx.x * blockDim.x + threadIdx.x;
    if (i < BSZ * NPIX) {
        const int p = i % NPIX;
        out[i] = acc[i] / acc[(size_t)BSZ * NPIX + p];
    }
}

// ---------------- launch ----------------

extern "C" void kernel_launch(void* const* d_in, const int* in_sizes, int n_in,
                              void* d_out, int out_size, void* d_ws, size_t ws_size,
                              hipStream_t stream) {
    const float* sino = (const float*)d_in[0];
    const float* vals = (const float*)d_in[1];
    const int*   rows = (const int*)d_in[2];
    const int*   cols = (const int*)d_in[3];
    float* out = (float*)d_out;

    // workspace layout (bytes, all 16B-aligned):
    //   rec    : NNZ * 8                  = 160,000,000
    //   sino_b : SINO * 16                =   8,208,000
    //   acc    : NBIN * RB_PX * 6 * 4     =  12,582,912
    //   cnt    : SCAT_BLOCKS * NBIN * 4   =     524,288
    //   base   : SCAT_BLOCKS * NBIN * 4   =     524,288
    //   tot    : NBIN * 4
    //   binoff : (NBIN+1) * 4
    const size_t rec_b    = (size_t)NNZ * 8;
    const size_t sino_b_b = (size_t)SINO * 16;
    const size_t acc_b    = (size_t)NBIN * RB_PX * 6 * 4;
    const size_t cnt_b    = (size_t)SCAT_BLOCKS * NBIN * 4;
    const size_t need = rec_b + sino_b_b + acc_b + 2 * cnt_b + (size_t)(NBIN + NBIN + 1 + 8) * 4;

    if (ws_size >= need) {
        char* w = (char*)d_ws;
        f32x2*    rec    = (f32x2*)w;                       w += rec_b;
        u32x4*    sinob  = (u32x4*)w;                       w += sino_b_b;
        float*    acc    = (float*)w;                       w += acc_b;
        unsigned* cnt    = (unsigned*)w;                    w += cnt_b;
        unsigned* base   = (unsigned*)w;                    w += cnt_b;
        unsigned* tot    = (unsigned*)w;                    w += (size_t)NBIN * 4;
        unsigned* binoff = (unsigned*)w;

        k_sino_bf16<<<(SINO + 255) / 256, 256, 0, stream>>>(sino, sinob);
        k_count<<<SCAT_BLOCKS, SCAT_THREADS, 0, stream>>>(rows, cols, cnt);
        k_tot<<<NBIN, SCAT_BLOCKS, 0, stream>>>(cnt, tot);
        k_scan<<<1, NBIN, 0, stream>>>(tot, binoff);
        k_base<<<NBIN, SCAT_BLOCKS, 0, stream>>>(cnt, binoff, base);
        k_scatter<<<SCAT_BLOCKS, SCAT_THREADS, 0, stream>>>(vals, rows, cols, base, rec);
        k_accum<<<NBIN, ACC_THREADS, 0, stream>>>(rec, sinob, binoff, acc);
        k_reduce<<<(NPIX + 255) / 256, 256, 0, stream>>>(acc, out);
    } else {
        float* acc = (float*)d_ws;
        (void)hipMemsetAsync(acc, 0, (size_t)(BSZ + 1) * NPIX * sizeof(float), stream);
        bp_scatter_fb_kernel<<<2048, 256, 0, stream>>>(sino, vals, rows, cols, acc);
        bp_divide_fb_kernel<<<(BSZ * NPIX + 255) / 256, 256, 0, stream>>>(acc, out);
    }
}